// Round 1
// baseline (2350.104 us; speedup 1.0000x reference)
//
#include <hip/hip_runtime.h>
#include <math.h>

__device__ __forceinline__ float sigf(float x) { return 1.0f / (1.0f + expf(-x)); }

// ---------------- Encoder GEMM1: C = relu(X @ W + b) ----------------
// X:[16384,1024] W:[1024,512] C:[16384,512]
__global__ __launch_bounds__(256) void k_gemm1(const float* __restrict__ X,
                                               const float* __restrict__ W,
                                               const float* __restrict__ Bv,
                                               float* __restrict__ C)
{
  const int K = 1024, N = 512;
  __shared__ float As[8][132];
  __shared__ float Bs[8][132];
  int tid = threadIdx.x;
  int bm = blockIdx.x >> 2;   // 128 row-blocks
  int bn = blockIdx.x & 3;    // 4 col-blocks
  int tx = tid & 15, ty = tid >> 4;
  int arow = tid >> 1, acol4 = (tid & 1) * 4;
  int bkk = tid >> 5, bn4 = (tid & 31) * 4;
  const float* Xb = X + (size_t)(bm * 128) * K;
  const float* Wb = W + bn * 128;
  float acc[8][8];
#pragma unroll
  for (int i = 0; i < 8; i++)
#pragma unroll
    for (int j2 = 0; j2 < 8; j2++) acc[i][j2] = 0.f;
  for (int k0 = 0; k0 < K; k0 += 8) {
    float4 av = *(const float4*)(Xb + (size_t)arow * K + k0 + acol4);
    float4 bv = *(const float4*)(Wb + (size_t)(k0 + bkk) * N + bn4);
    As[acol4 + 0][arow] = av.x;
    As[acol4 + 1][arow] = av.y;
    As[acol4 + 2][arow] = av.z;
    As[acol4 + 3][arow] = av.w;
    *(float4*)(&Bs[bkk][bn4]) = bv;
    __syncthreads();
#pragma unroll
    for (int kk = 0; kk < 8; kk++) {
      float a[8], b[8];
      *(float4*)(a)     = *(const float4*)(&As[kk][ty * 8]);
      *(float4*)(a + 4) = *(const float4*)(&As[kk][ty * 8 + 4]);
      *(float4*)(b)     = *(const float4*)(&Bs[kk][tx * 8]);
      *(float4*)(b + 4) = *(const float4*)(&Bs[kk][tx * 8 + 4]);
#pragma unroll
      for (int i = 0; i < 8; i++)
#pragma unroll
        for (int j2 = 0; j2 < 8; j2++) acc[i][j2] = fmaf(a[i], b[j2], acc[i][j2]);
    }
    __syncthreads();
  }
  int crow0 = bm * 128 + ty * 8;
  int ccol0 = bn * 128 + tx * 8;
#pragma unroll
  for (int i = 0; i < 8; i++)
#pragma unroll
    for (int j2 = 0; j2 < 8; j2++) {
      float v = acc[i][j2] + Bv[ccol0 + j2];
      C[(size_t)(crow0 + i) * N + ccol0 + j2] = v > 0.f ? v : 0.f;
    }
}

// ---------------- Encoder GEMM2: zp[b][t][c] = C1 @ W2 + b2 (t<32) ----------------
// A:[16384,512] W:[512,128] zp:[512][33][128]
__global__ __launch_bounds__(256) void k_gemm2(const float* __restrict__ A,
                                               const float* __restrict__ W,
                                               const float* __restrict__ Bv,
                                               float* __restrict__ zp)
{
  const int K = 512, N = 128;
  __shared__ float As[8][132];
  __shared__ float Bs[8][132];
  int tid = threadIdx.x;
  int bm = blockIdx.x;
  int tx = tid & 15, ty = tid >> 4;
  int arow = tid >> 1, acol4 = (tid & 1) * 4;
  int bkk = tid >> 5, bn4 = (tid & 31) * 4;
  const float* Ab = A + (size_t)(bm * 128) * K;
  float acc[8][8];
#pragma unroll
  for (int i = 0; i < 8; i++)
#pragma unroll
    for (int j2 = 0; j2 < 8; j2++) acc[i][j2] = 0.f;
  for (int k0 = 0; k0 < K; k0 += 8) {
    float4 av = *(const float4*)(Ab + (size_t)arow * K + k0 + acol4);
    float4 bv = *(const float4*)(W + (size_t)(k0 + bkk) * N + bn4);
    As[acol4 + 0][arow] = av.x;
    As[acol4 + 1][arow] = av.y;
    As[acol4 + 2][arow] = av.z;
    As[acol4 + 3][arow] = av.w;
    *(float4*)(&Bs[bkk][bn4]) = bv;
    __syncthreads();
#pragma unroll
    for (int kk = 0; kk < 8; kk++) {
      float a[8], b[8];
      *(float4*)(a)     = *(const float4*)(&As[kk][ty * 8]);
      *(float4*)(a + 4) = *(const float4*)(&As[kk][ty * 8 + 4]);
      *(float4*)(b)     = *(const float4*)(&Bs[kk][tx * 8]);
      *(float4*)(b + 4) = *(const float4*)(&Bs[kk][tx * 8 + 4]);
#pragma unroll
      for (int i = 0; i < 8; i++)
#pragma unroll
        for (int j2 = 0; j2 < 8; j2++) acc[i][j2] = fmaf(a[i], b[j2], acc[i][j2]);
    }
    __syncthreads();
  }
  int ccol0 = tx * 8;
#pragma unroll
  for (int i = 0; i < 8; i++) {
    int r = bm * 128 + ty * 8 + i;
    int b = r >> 5, tt = r & 31;
#pragma unroll
    for (int j2 = 0; j2 < 8; j2++) {
      zp[(size_t)b * (33 * 128) + tt * 128 + ccol0 + j2] = acc[i][j2] + Bv[ccol0 + j2];
    }
  }
}

// ---------------- Gram: G[b][t][tp] = z_t . z_tp  (1<=t<=31, tp<t) ----------------
__global__ __launch_bounds__(256) void k_gram(const float* __restrict__ zp,
                                              float* __restrict__ G)
{
  __shared__ float zl[32][128];
  int b = blockIdx.x, tid = threadIdx.x;
  const float* zb = zp + (size_t)b * (33 * 128);
  for (int i = tid; i < 32 * 128; i += 256) (&zl[0][0])[i] = zb[i];
  __syncthreads();
  for (int p = tid; p < 496; p += 256) {
    int t = 1;
    while (p >= t * (t + 1) / 2) t++;
    int tp = p - t * (t - 1) / 2;
    const float* za = &zl[t][0];
    const float* zc = &zl[tp][0];
    float s = 0.f;
#pragma unroll 4
    for (int c = 0; c < 128; c += 4) {
      s += za[c] * zc[c] + za[c + 1] * zc[c + 1] + za[c + 2] * zc[c + 2] + za[c + 3] * zc[c + 3];
    }
    G[(size_t)b * 1089 + t * 33 + tp] = s;
  }
}

// ---------------- Persistent recurrence: 128 WGs x 512 thr, 4 batch rows each ----------------
__global__ __launch_bounds__(512) void k_rec(
    const float* __restrict__ Wx, const float* __restrict__ lb,
    const float* __restrict__ kW, const float* __restrict__ kb,
    const float* __restrict__ gW, const float* __restrict__ gb,
    const float* __restrict__ yW, const float* __restrict__ yb,
    const float* __restrict__ cgp, const float* __restrict__ cbp,
    const float* __restrict__ G, float* __restrict__ Mk,
    float* __restrict__ out)
{
  __shared__ float key_rT[257][4];  // [k][row]
  __shared__ float hT[512][4];      // [k][row]
  __shared__ float4 red4[512];
  __shared__ float warr[4][33];
  __shared__ float gate[4];
  __shared__ float ysh[4][4];
  const int tid = threadIdx.x;
  const int row0 = blockIdx.x * 4;
  const float cg = cgp[0], cbv = cbp[0];
  for (int i = tid; i < 257 * 4; i += 512) (&key_rT[0][0])[i] = 0.f;
  __syncthreads();
  const int j = tid;  // gate column 0..511
  const float bi = lb[j], bc = lb[1024 + j], bo = lb[1536 + j];

  for (int t = 0; t <= 32; t++) {
    // ---- Phase A: gates(i,c,o) = key_r @ Wx + b  -> h (f-gate is dead in the reference)
    float accI[4], accC[4], accO[4];
#pragma unroll
    for (int r = 0; r < 4; r++) { accI[r] = bi; accC[r] = bc; accO[r] = bo; }
    for (int k = 0; k < 257; k++) {
      float4 kr = *(const float4*)(&key_rT[k][0]);
      float wi = Wx[(size_t)k * 2048 + j];
      float wc = Wx[(size_t)k * 2048 + 1024 + j];
      float wo = Wx[(size_t)k * 2048 + 1536 + j];
      float krr[4] = {kr.x, kr.y, kr.z, kr.w};
#pragma unroll
      for (int r = 0; r < 4; r++) {
        accI[r] = fmaf(krr[r], wi, accI[r]);
        accC[r] = fmaf(krr[r], wc, accC[r]);
        accO[r] = fmaf(krr[r], wo, accO[r]);
      }
    }
    {
      float hh[4];
#pragma unroll
      for (int r = 0; r < 4; r++) {
        float cn = sigf(accI[r]) * tanhf(accC[r]);
        hh[r] = sigf(accO[r]) * tanhf(cn);
      }
      *(float4*)(&hT[j][0]) = make_float4(hh[0], hh[1], hh[2], hh[3]);
    }
    __syncthreads();

    // ---- Phase B: key_w -> Mk[:,t,:], gate scalar (skip at t==32)
    if (t < 32) {
      int r = tid >> 7;
      int n2 = (tid & 127) * 2;
      float a0 = kb[n2], a1 = kb[n2 + 1];
      for (int k = 0; k < 512; k++) {
        float hvk = hT[k][r];
        float2 wv = *(const float2*)(kW + (size_t)k * 256 + n2);
        a0 = fmaf(hvk, wv.x, a0);
        a1 = fmaf(hvk, wv.y, a1);
      }
      *(float2*)(Mk + (size_t)(row0 + r) * (32 * 256) + t * 256 + n2) = make_float2(a0, a1);
      // gate = sigmoid(h . gW + gb), one per row, via float4 tree
      float gwv = gW[tid];
      red4[tid] = make_float4(hT[tid][0] * gwv, hT[tid][1] * gwv,
                              hT[tid][2] * gwv, hT[tid][3] * gwv);
      __syncthreads();
      for (int s = 256; s > 0; s >>= 1) {
        if (tid < s) {
          float4 q = red4[tid + s];
          float4 pp = red4[tid];
          pp.x += q.x; pp.y += q.y; pp.z += q.z; pp.w += q.w;
          red4[tid] = pp;
        }
        __syncthreads();
      }
      if (tid < 4) gate[tid] = sigf(((const float*)&red4[0])[tid] + gb[0]);
      __syncthreads();
    }

    // ---- Phase C: softmax over valid slots + key_r update (t in [1,31])
    if (t >= 1 && t < 32) {
      if (tid < 256) {
        int wv = tid >> 6, lane = tid & 63;
        const float* gr = G + (size_t)(row0 + wv) * 1089 + t * 33;
        float s = (lane < t) ? gr[lane] : -3.0e38f;
        float mx = s;
#pragma unroll
        for (int off = 32; off > 0; off >>= 1) mx = fmaxf(mx, __shfl_xor(mx, off));
        float e = (lane < t) ? expf(s - mx) : 0.f;
        float se = e;
#pragma unroll
        for (int off = 32; off > 0; off >>= 1) se += __shfl_xor(se, off);
        float w = e / se;
        float wc2 = (lane < t) ? w * sigf(fmaf(s, cg, cbv)) : 0.f;
#pragma unroll
        for (int off = 32; off > 0; off >>= 1) wc2 += __shfl_xor(wc2, off);
        if (lane < 33) warr[wv][lane] = (lane < t) ? w : 0.f;
        if (lane == 0) key_rT[256][wv] = gate[wv] * wc2;
      }
      __syncthreads();
      int r = tid >> 7;
      int n2 = (tid & 127) * 2;
      float a0 = 0.f, a1 = 0.f;
      const float* mkb = Mk + (size_t)(row0 + r) * (32 * 256) + n2;
      for (int tp = 0; tp < t; tp++) {
        float w = warr[r][tp];
        float2 m = *(const float2*)(mkb + tp * 256);
        a0 = fmaf(w, m.x, a0);
        a1 = fmaf(w, m.y, a1);
      }
      float gr2 = gate[r];
      key_rT[n2][r] = gr2 * a0;
      key_rT[n2 + 1][r] = gr2 * a1;
    }
    // t==0: key_r stays zero (matches reference's where(t==0, 0))
    __syncthreads();

    // ---- Phase D: final outputs at t==32
    if (t == 32) {
      for (int r = 0; r < 4; r++) {
        float hvk = hT[tid][r];
        red4[tid] = make_float4(hvk * yW[tid * 4 + 0], hvk * yW[tid * 4 + 1],
                                hvk * yW[tid * 4 + 2], hvk * yW[tid * 4 + 3]);
        __syncthreads();
        for (int s = 256; s > 0; s >>= 1) {
          if (tid < s) {
            float4 q = red4[tid + s];
            float4 pp = red4[tid];
            pp.x += q.x; pp.y += q.y; pp.z += q.z; pp.w += q.w;
            red4[tid] = pp;
          }
          __syncthreads();
        }
        if (tid == 0) {
          float4 q = red4[0];
          ysh[r][0] = q.x + yb[0];
          ysh[r][1] = q.y + yb[1];
          ysh[r][2] = q.z + yb[2];
          ysh[r][3] = q.w + yb[3];
        }
        __syncthreads();
      }
      if (tid < 4) {
        int r = tid;
        float v0 = ysh[r][0], v1 = ysh[r][1], v2 = ysh[r][2], v3 = ysh[r][3];
        out[(row0 + r) * 4 + 0] = v0;
        out[(row0 + r) * 4 + 1] = v1;
        out[(row0 + r) * 4 + 2] = v2;
        out[(row0 + r) * 4 + 3] = v3;
        int bi2 = 0; float bv2 = v0;
        if (v1 > bv2) { bv2 = v1; bi2 = 1; }
        if (v2 > bv2) { bv2 = v2; bi2 = 2; }
        if (v3 > bv2) { bv2 = v3; bi2 = 3; }
        out[2048 + row0 + r] = (float)bi2;
      }
    }
  }
}

extern "C" void kernel_launch(void* const* d_in, const int* in_sizes, int n_in,
                              void* d_out, int out_size, void* d_ws, size_t ws_size,
                              hipStream_t stream)
{
  const float* x  = (const float*)d_in[0];
  const float* w1 = (const float*)d_in[1];
  const float* b1 = (const float*)d_in[2];
  const float* w2 = (const float*)d_in[3];
  const float* b2 = (const float*)d_in[4];
  const float* Wx = (const float*)d_in[5];
  const float* lb = (const float*)d_in[6];
  const float* kW = (const float*)d_in[7];
  const float* kb = (const float*)d_in[8];
  const float* gW = (const float*)d_in[9];
  const float* gb = (const float*)d_in[10];
  const float* yW = (const float*)d_in[11];
  const float* yb = (const float*)d_in[12];
  const float* cg = (const float*)d_in[13];
  const float* cb = (const float*)d_in[14];
  float* out = (float*)d_out;
  char* ws = (char*)d_ws;
  // ws layout (42.3 MB total):
  //  [0, 33.5MB)   C1 (encoder hidden) -- dead after k_gemm2, region reused:
  //     [0, 16.8MB)        Mk  (key memory, written/read only by k_rec)
  //     [20.97MB, 23.2MB)  Gram (written by k_gram after C1 dead)
  //  [33.5MB, 42.2MB) z_pad
  float* C1   = (float*)(ws);
  float* Mk   = (float*)(ws);
  float* Gram = (float*)(ws + 20971520);
  float* zp   = (float*)(ws + 33554432);

  hipLaunchKernelGGL(k_gemm1, dim3(512), dim3(256), 0, stream, x, w1, b1, C1);
  hipLaunchKernelGGL(k_gemm2, dim3(128), dim3(256), 0, stream, C1, w2, b2, zp);
  hipLaunchKernelGGL(k_gram, dim3(512), dim3(256), 0, stream, zp, Gram);
  hipLaunchKernelGGL(k_rec, dim3(128), dim3(512), 0, stream,
                     Wx, lb, kW, kb, gW, gb, yW, yb, cg, cb, Gram, Mk, out);
}

// Round 2
// 1905.752 us; speedup vs baseline: 1.2332x; 1.2332x over previous
//
#include <hip/hip_runtime.h>
#include <math.h>

__device__ __forceinline__ float sigf(float x) { return 1.0f / (1.0f + expf(-x)); }

// ---------------- Encoder GEMM1: C = relu(X @ W + b) ----------------
// X:[16384,1024] W:[1024,512] C:[16384,512]
__global__ __launch_bounds__(256) void k_gemm1(const float* __restrict__ X,
                                               const float* __restrict__ W,
                                               const float* __restrict__ Bv,
                                               float* __restrict__ C)
{
  const int K = 1024, N = 512;
  __shared__ float As[8][132];
  __shared__ float Bs[8][132];
  int tid = threadIdx.x;
  int bm = blockIdx.x >> 2;
  int bn = blockIdx.x & 3;
  int tx = tid & 15, ty = tid >> 4;
  int arow = tid >> 1, acol4 = (tid & 1) * 4;
  int bkk = tid >> 5, bn4 = (tid & 31) * 4;
  const float* Xb = X + (size_t)(bm * 128) * K;
  const float* Wb = W + bn * 128;
  float acc[8][8];
#pragma unroll
  for (int i = 0; i < 8; i++)
#pragma unroll
    for (int j2 = 0; j2 < 8; j2++) acc[i][j2] = 0.f;
  for (int k0 = 0; k0 < K; k0 += 8) {
    float4 av = *(const float4*)(Xb + (size_t)arow * K + k0 + acol4);
    float4 bv = *(const float4*)(Wb + (size_t)(k0 + bkk) * N + bn4);
    As[acol4 + 0][arow] = av.x;
    As[acol4 + 1][arow] = av.y;
    As[acol4 + 2][arow] = av.z;
    As[acol4 + 3][arow] = av.w;
    *(float4*)(&Bs[bkk][bn4]) = bv;
    __syncthreads();
#pragma unroll
    for (int kk = 0; kk < 8; kk++) {
      float a[8], b[8];
      *(float4*)(a)     = *(const float4*)(&As[kk][ty * 8]);
      *(float4*)(a + 4) = *(const float4*)(&As[kk][ty * 8 + 4]);
      *(float4*)(b)     = *(const float4*)(&Bs[kk][tx * 8]);
      *(float4*)(b + 4) = *(const float4*)(&Bs[kk][tx * 8 + 4]);
#pragma unroll
      for (int i = 0; i < 8; i++)
#pragma unroll
        for (int j2 = 0; j2 < 8; j2++) acc[i][j2] = fmaf(a[i], b[j2], acc[i][j2]);
    }
    __syncthreads();
  }
  int crow0 = bm * 128 + ty * 8;
  int ccol0 = bn * 128 + tx * 8;
#pragma unroll
  for (int i = 0; i < 8; i++)
#pragma unroll
    for (int j2 = 0; j2 < 8; j2++) {
      float v = acc[i][j2] + Bv[ccol0 + j2];
      C[(size_t)(crow0 + i) * N + ccol0 + j2] = v > 0.f ? v : 0.f;
    }
}

// ---------------- Encoder GEMM2: zp[b][t][c] = C1 @ W2 + b2 ----------------
__global__ __launch_bounds__(256) void k_gemm2(const float* __restrict__ A,
                                               const float* __restrict__ W,
                                               const float* __restrict__ Bv,
                                               float* __restrict__ zp)
{
  const int K = 512, N = 128;
  __shared__ float As[8][132];
  __shared__ float Bs[8][132];
  int tid = threadIdx.x;
  int bm = blockIdx.x;
  int tx = tid & 15, ty = tid >> 4;
  int arow = tid >> 1, acol4 = (tid & 1) * 4;
  int bkk = tid >> 5, bn4 = (tid & 31) * 4;
  const float* Ab = A + (size_t)(bm * 128) * K;
  float acc[8][8];
#pragma unroll
  for (int i = 0; i < 8; i++)
#pragma unroll
    for (int j2 = 0; j2 < 8; j2++) acc[i][j2] = 0.f;
  for (int k0 = 0; k0 < K; k0 += 8) {
    float4 av = *(const float4*)(Ab + (size_t)arow * K + k0 + acol4);
    float4 bv = *(const float4*)(W + (size_t)(k0 + bkk) * N + bn4);
    As[acol4 + 0][arow] = av.x;
    As[acol4 + 1][arow] = av.y;
    As[acol4 + 2][arow] = av.z;
    As[acol4 + 3][arow] = av.w;
    *(float4*)(&Bs[bkk][bn4]) = bv;
    __syncthreads();
#pragma unroll
    for (int kk = 0; kk < 8; kk++) {
      float a[8], b[8];
      *(float4*)(a)     = *(const float4*)(&As[kk][ty * 8]);
      *(float4*)(a + 4) = *(const float4*)(&As[kk][ty * 8 + 4]);
      *(float4*)(b)     = *(const float4*)(&Bs[kk][tx * 8]);
      *(float4*)(b + 4) = *(const float4*)(&Bs[kk][tx * 8 + 4]);
#pragma unroll
      for (int i = 0; i < 8; i++)
#pragma unroll
        for (int j2 = 0; j2 < 8; j2++) acc[i][j2] = fmaf(a[i], b[j2], acc[i][j2]);
    }
    __syncthreads();
  }
  int ccol0 = tx * 8;
#pragma unroll
  for (int i = 0; i < 8; i++) {
    int r = bm * 128 + ty * 8 + i;
    int b = r >> 5, tt = r & 31;
#pragma unroll
    for (int j2 = 0; j2 < 8; j2++) {
      zp[(size_t)b * (33 * 128) + tt * 128 + ccol0 + j2] = acc[i][j2] + Bv[ccol0 + j2];
    }
  }
}

// ---------------- Gram + softmax precompute ----------------
// warr[b][t][tp] = softmax weight (tp<t), wc[b][t] = sum_tp w*sigmoid(s*cg+cb)
__global__ __launch_bounds__(256) void k_gram(const float* __restrict__ zp,
                                              float* __restrict__ warr,
                                              float* __restrict__ wc,
                                              const float* __restrict__ cgp,
                                              const float* __restrict__ cbp)
{
  __shared__ float zl[32][128];
  __shared__ float sg[32][32];
  int b = blockIdx.x, tid = threadIdx.x;
  const float* zb = zp + (size_t)b * (33 * 128);
  for (int i = tid; i < 32 * 128; i += 256) (&zl[0][0])[i] = zb[i];
  __syncthreads();
  for (int p = tid; p < 496; p += 256) {
    int t = 1;
    while (p >= t * (t + 1) / 2) t++;
    int tp = p - t * (t - 1) / 2;
    const float* za = &zl[t][0];
    const float* zc = &zl[tp][0];
    float s = 0.f;
#pragma unroll 4
    for (int c = 0; c < 128; c += 4) {
      s += za[c] * zc[c] + za[c + 1] * zc[c + 1] + za[c + 2] * zc[c + 2] + za[c + 3] * zc[c + 3];
    }
    sg[t][tp] = s;
  }
  __syncthreads();
  if (tid >= 1 && tid < 32) {
    int t = tid;
    float cg = cgp[0], cb = cbp[0];
    float m = -3.0e38f;
    for (int tp = 0; tp < t; tp++) m = fmaxf(m, sg[t][tp]);
    float se = 0.f;
    for (int tp = 0; tp < t; tp++) se += expf(sg[t][tp] - m);
    float inv = 1.0f / se;
    float wcs = 0.f;
    for (int tp = 0; tp < t; tp++) {
      float s = sg[t][tp];
      float w = expf(s - m) * inv;
      warr[(size_t)b * 1024 + t * 32 + tp] = w;
      wcs = fmaf(w, sigf(fmaf(s, cg, cb)), wcs);
    }
    wc[b * 32 + t] = wcs;
  }
}

// ---------------- per-step: gates GEMM + activation -> h ----------------
// h[512][512]; 256 WGs x 1024 thr; WG = 16 rows x 64 jcols; 1 (i,c,o) triple/thread
__global__ __launch_bounds__(1024) void k_gates(const float* __restrict__ Wx,
                                                const float* __restrict__ lb,
                                                const float* __restrict__ keyr,
                                                float* __restrict__ h, int t)
{
  __shared__ float krs[16][264];
  const int tid = threadIdx.x;
  const int jc = tid & 63;
  const int r16 = tid >> 6;          // 0..15
  const int rt = blockIdx.x >> 3;    // 32 row tiles
  const int ct = blockIdx.x & 7;     // 8 col tiles
  const int jcol = ct * 64 + jc;
  const int row = rt * 16 + r16;
  float accI = lb[jcol], accC = lb[1024 + jcol], accO = lb[1536 + jcol];
  if (t > 0) {
    for (int k = jc; k < 257; k += 64) krs[r16][k] = keyr[row * 257 + k];
    __syncthreads();
    const float* wp = Wx + jcol;
    const float* kp = &krs[r16][0];
#pragma unroll 8
    for (int k = 0; k < 256; k++) {
      float wi = wp[(size_t)k * 2048];
      float wcc = wp[(size_t)k * 2048 + 1024];
      float wo = wp[(size_t)k * 2048 + 1536];
      float kr = kp[k];
      accI = fmaf(kr, wi, accI);
      accC = fmaf(kr, wcc, accC);
      accO = fmaf(kr, wo, accO);
    }
    {
      float kr = kp[256];
      accI = fmaf(kr, wp[256 * 2048], accI);
      accC = fmaf(kr, wp[256 * 2048 + 1024], accC);
      accO = fmaf(kr, wp[256 * 2048 + 1536], accO);
    }
  }
  float cn = sigf(accI) * tanhf(accC);
  h[row * 512 + jcol] = sigf(accO) * tanhf(cn);
}

// ---------------- per-step: key_w -> Mk[t], gate, key_r update ----------------
// 512 WGs x 256 thr; WG = 8 rows x 32 cols
__global__ __launch_bounds__(256) void k_update(const float* __restrict__ h,
                                                const float* __restrict__ kW,
                                                const float* __restrict__ kb,
                                                const float* __restrict__ gW,
                                                const float* __restrict__ gb,
                                                const float* __restrict__ warr,
                                                const float* __restrict__ wc,
                                                float* __restrict__ Mk,
                                                float* __restrict__ keyr, int t)
{
  __shared__ float hs[8][516];
  __shared__ float red[256];
  __shared__ float ww[8][32];
  __shared__ float gsh[8];
  const int tid = threadIdx.x;
  const int c32 = tid & 31, r8 = tid >> 5;
  const int rt = blockIdx.x >> 3, ct = blockIdx.x & 7;
  const int row = rt * 8 + r8;
  const int col = ct * 32 + c32;
  for (int k = c32; k < 512; k += 32) hs[r8][k] = h[row * 512 + k];
  ww[r8][c32] = (c32 < t) ? warr[(size_t)row * 1024 + t * 32 + c32] : 0.f;
  __syncthreads();
  // key_w GEMM (K=512)
  float acc = kb[col];
  const float* hp = &hs[r8][0];
#pragma unroll 8
  for (int k = 0; k < 512; k++) acc = fmaf(hp[k], kW[k * 256 + col], acc);
  Mk[(size_t)row * 8192 + t * 256 + col] = acc;
  // gate = sigmoid(h . gW + gb)
  float gp = 0.f;
  for (int k = c32; k < 512; k += 32) gp = fmaf(hp[k], gW[k], gp);
  red[tid] = gp;
  __syncthreads();
  for (int s = 16; s > 0; s >>= 1) {
    if (c32 < s) red[tid] += red[tid + s];
    __syncthreads();
  }
  if (c32 == 0) gsh[r8] = sigf(red[tid] + gb[0]);
  __syncthreads();
  // key_r update
  if (t == 0) {
    keyr[row * 257 + col] = 0.f;
    if (ct == 0 && c32 == 0) keyr[row * 257 + 256] = 0.f;
  } else {
    float a = 0.f;
    const float* mkb = Mk + (size_t)row * 8192 + col;
#pragma unroll 4
    for (int tp = 0; tp < t; tp++) a = fmaf(ww[r8][tp], mkb[tp * 256], a);
    float g = gsh[r8];
    keyr[row * 257 + col] = g * a;
    if (ct == 0 && c32 == 0) keyr[row * 257 + 256] = g * wc[row * 32 + t];
  }
}

// ---------------- final: y = h @ yW + yb, argmax ----------------
__global__ __launch_bounds__(256) void k_y(const float* __restrict__ h,
                                           const float* __restrict__ yW,
                                           const float* __restrict__ yb,
                                           float* __restrict__ out)
{
  int tid = threadIdx.x;
  int wave = tid >> 6, lane = tid & 63;
  int row = blockIdx.x * 4 + wave;
  float a0 = 0.f, a1 = 0.f, a2 = 0.f, a3 = 0.f;
  for (int k = lane; k < 512; k += 64) {
    float hv = h[row * 512 + k];
    float4 w4 = *(const float4*)(yW + k * 4);
    a0 = fmaf(hv, w4.x, a0);
    a1 = fmaf(hv, w4.y, a1);
    a2 = fmaf(hv, w4.z, a2);
    a3 = fmaf(hv, w4.w, a3);
  }
#pragma unroll
  for (int off = 32; off > 0; off >>= 1) {
    a0 += __shfl_xor(a0, off);
    a1 += __shfl_xor(a1, off);
    a2 += __shfl_xor(a2, off);
    a3 += __shfl_xor(a3, off);
  }
  if (lane == 0) {
    a0 += yb[0]; a1 += yb[1]; a2 += yb[2]; a3 += yb[3];
    out[row * 4 + 0] = a0;
    out[row * 4 + 1] = a1;
    out[row * 4 + 2] = a2;
    out[row * 4 + 3] = a3;
    int bi = 0; float bv = a0;
    if (a1 > bv) { bv = a1; bi = 1; }
    if (a2 > bv) { bv = a2; bi = 2; }
    if (a3 > bv) { bv = a3; bi = 3; }
    out[2048 + row] = (float)bi;
  }
}

extern "C" void kernel_launch(void* const* d_in, const int* in_sizes, int n_in,
                              void* d_out, int out_size, void* d_ws, size_t ws_size,
                              hipStream_t stream)
{
  const float* x  = (const float*)d_in[0];
  const float* w1 = (const float*)d_in[1];
  const float* b1 = (const float*)d_in[2];
  const float* w2 = (const float*)d_in[3];
  const float* b2 = (const float*)d_in[4];
  const float* Wx = (const float*)d_in[5];
  const float* lb = (const float*)d_in[6];
  const float* kW = (const float*)d_in[7];
  const float* kb = (const float*)d_in[8];
  const float* gW = (const float*)d_in[9];
  const float* gb = (const float*)d_in[10];
  const float* yW = (const float*)d_in[11];
  const float* yb = (const float*)d_in[12];
  const float* cg = (const float*)d_in[13];
  const float* cb = (const float*)d_in[14];
  float* out = (float*)d_out;
  char* ws = (char*)d_ws;
  // ws layout:
  //  C1 @ [0, 33.55MB)  (dead after k_gemm2; region reused below)
  //    Mk   @ 0          (16.78MB)  512x32x256 f32
  //    warr @ 16777216   (2MB)      512x32x32 f32
  //    wc   @ 18874368   (64KB)     512x32 f32
  //    keyr @ 18939904   (514KB)    512x257 f32
  //    h    @ 19466240   (1MB)      512x512 f32
  //  zp @ 33554432       (8.65MB)   512x33x128 f32
  float* C1   = (float*)(ws);
  float* Mk   = (float*)(ws);
  float* warr = (float*)(ws + 16777216);
  float* wcb  = (float*)(ws + 18874368);
  float* keyr = (float*)(ws + 18939904);
  float* h    = (float*)(ws + 19466240);
  float* zp   = (float*)(ws + 33554432);

  hipLaunchKernelGGL(k_gemm1, dim3(512), dim3(256), 0, stream, x, w1, b1, C1);
  hipLaunchKernelGGL(k_gemm2, dim3(128), dim3(256), 0, stream, C1, w2, b2, zp);
  hipLaunchKernelGGL(k_gram, dim3(512), dim3(256), 0, stream, zp, warr, wcb, cg, cb);
  for (int t = 0; t <= 32; t++) {
    hipLaunchKernelGGL(k_gates, dim3(256), dim3(1024), 0, stream, Wx, lb, keyr, h, t);
    if (t < 32) {
      hipLaunchKernelGGL(k_update, dim3(512), dim3(256), 0, stream,
                         h, kW, kb, gW, gb, warr, wcb, Mk, keyr, t);
    }
  }
  hipLaunchKernelGGL(k_y, dim3(128), dim3(256), 0, stream, h, yW, yb, out);
}

// Round 3
// 1468.614 us; speedup vs baseline: 1.6002x; 1.2977x over previous
//
#include <hip/hip_runtime.h>
#include <math.h>

__device__ __forceinline__ float sigf(float x) { return 1.0f / (1.0f + expf(-x)); }
__device__ __forceinline__ float4 f4add(float4 a, float4 b) {
  return make_float4(a.x + b.x, a.y + b.y, a.z + b.z, a.w + b.w);
}
__device__ __forceinline__ float4 f4fma(float s, float4 b, float4 a) {
  return make_float4(fmaf(s, b.x, a.x), fmaf(s, b.y, a.y), fmaf(s, b.z, a.z), fmaf(s, b.w, a.w));
}

// ---------------- Encoder GEMM1: C = relu(X @ W + b) ----------------
__global__ __launch_bounds__(256) void k_gemm1(const float* __restrict__ X,
                                               const float* __restrict__ W,
                                               const float* __restrict__ Bv,
                                               float* __restrict__ C)
{
  const int K = 1024, N = 512;
  __shared__ float As[8][132];
  __shared__ float Bs[8][132];
  int tid = threadIdx.x;
  int bm = blockIdx.x >> 2;
  int bn = blockIdx.x & 3;
  int tx = tid & 15, ty = tid >> 4;
  int arow = tid >> 1, acol4 = (tid & 1) * 4;
  int bkk = tid >> 5, bn4 = (tid & 31) * 4;
  const float* Xb = X + (size_t)(bm * 128) * K;
  const float* Wb = W + bn * 128;
  float acc[8][8];
#pragma unroll
  for (int i = 0; i < 8; i++)
#pragma unroll
    for (int j2 = 0; j2 < 8; j2++) acc[i][j2] = 0.f;
  for (int k0 = 0; k0 < K; k0 += 8) {
    float4 av = *(const float4*)(Xb + (size_t)arow * K + k0 + acol4);
    float4 bv = *(const float4*)(Wb + (size_t)(k0 + bkk) * N + bn4);
    As[acol4 + 0][arow] = av.x;
    As[acol4 + 1][arow] = av.y;
    As[acol4 + 2][arow] = av.z;
    As[acol4 + 3][arow] = av.w;
    *(float4*)(&Bs[bkk][bn4]) = bv;
    __syncthreads();
#pragma unroll
    for (int kk = 0; kk < 8; kk++) {
      float a[8], b[8];
      *(float4*)(a)     = *(const float4*)(&As[kk][ty * 8]);
      *(float4*)(a + 4) = *(const float4*)(&As[kk][ty * 8 + 4]);
      *(float4*)(b)     = *(const float4*)(&Bs[kk][tx * 8]);
      *(float4*)(b + 4) = *(const float4*)(&Bs[kk][tx * 8 + 4]);
#pragma unroll
      for (int i = 0; i < 8; i++)
#pragma unroll
        for (int j2 = 0; j2 < 8; j2++) acc[i][j2] = fmaf(a[i], b[j2], acc[i][j2]);
    }
    __syncthreads();
  }
  int crow0 = bm * 128 + ty * 8;
  int ccol0 = bn * 128 + tx * 8;
#pragma unroll
  for (int i = 0; i < 8; i++)
#pragma unroll
    for (int j2 = 0; j2 < 8; j2++) {
      float v = acc[i][j2] + Bv[ccol0 + j2];
      C[(size_t)(crow0 + i) * N + ccol0 + j2] = v > 0.f ? v : 0.f;
    }
}

// ---------------- Encoder GEMM2 ----------------
__global__ __launch_bounds__(256) void k_gemm2(const float* __restrict__ A,
                                               const float* __restrict__ W,
                                               const float* __restrict__ Bv,
                                               float* __restrict__ zp)
{
  const int K = 512, N = 128;
  __shared__ float As[8][132];
  __shared__ float Bs[8][132];
  int tid = threadIdx.x;
  int bm = blockIdx.x;
  int tx = tid & 15, ty = tid >> 4;
  int arow = tid >> 1, acol4 = (tid & 1) * 4;
  int bkk = tid >> 5, bn4 = (tid & 31) * 4;
  const float* Ab = A + (size_t)(bm * 128) * K;
  float acc[8][8];
#pragma unroll
  for (int i = 0; i < 8; i++)
#pragma unroll
    for (int j2 = 0; j2 < 8; j2++) acc[i][j2] = 0.f;
  for (int k0 = 0; k0 < K; k0 += 8) {
    float4 av = *(const float4*)(Ab + (size_t)arow * K + k0 + acol4);
    float4 bv = *(const float4*)(W + (size_t)(k0 + bkk) * N + bn4);
    As[acol4 + 0][arow] = av.x;
    As[acol4 + 1][arow] = av.y;
    As[acol4 + 2][arow] = av.z;
    As[acol4 + 3][arow] = av.w;
    *(float4*)(&Bs[bkk][bn4]) = bv;
    __syncthreads();
#pragma unroll
    for (int kk = 0; kk < 8; kk++) {
      float a[8], b[8];
      *(float4*)(a)     = *(const float4*)(&As[kk][ty * 8]);
      *(float4*)(a + 4) = *(const float4*)(&As[kk][ty * 8 + 4]);
      *(float4*)(b)     = *(const float4*)(&Bs[kk][tx * 8]);
      *(float4*)(b + 4) = *(const float4*)(&Bs[kk][tx * 8 + 4]);
#pragma unroll
      for (int i = 0; i < 8; i++)
#pragma unroll
        for (int j2 = 0; j2 < 8; j2++) acc[i][j2] = fmaf(a[i], b[j2], acc[i][j2]);
    }
    __syncthreads();
  }
  int ccol0 = tx * 8;
#pragma unroll
  for (int i = 0; i < 8; i++) {
    int r = bm * 128 + ty * 8 + i;
    int b = r >> 5, tt = r & 31;
#pragma unroll
    for (int j2 = 0; j2 < 8; j2++) {
      zp[(size_t)b * (33 * 128) + tt * 128 + ccol0 + j2] = acc[i][j2] + Bv[ccol0 + j2];
    }
  }
}

// ---------------- Gram + softmax precompute ----------------
__global__ __launch_bounds__(256) void k_gram(const float* __restrict__ zp,
                                              float* __restrict__ warr,
                                              float* __restrict__ wc,
                                              const float* __restrict__ cgp,
                                              const float* __restrict__ cbp)
{
  __shared__ float zl[32][128];
  __shared__ float sg[32][32];
  int b = blockIdx.x, tid = threadIdx.x;
  const float* zb = zp + (size_t)b * (33 * 128);
  for (int i = tid; i < 32 * 128; i += 256) (&zl[0][0])[i] = zb[i];
  __syncthreads();
  for (int p = tid; p < 496; p += 256) {
    int t = 1;
    while (p >= t * (t + 1) / 2) t++;
    int tp = p - t * (t - 1) / 2;
    const float* za = &zl[t][0];
    const float* zc = &zl[tp][0];
    float s = 0.f;
#pragma unroll 4
    for (int c = 0; c < 128; c += 4) {
      s += za[c] * zc[c] + za[c + 1] * zc[c + 1] + za[c + 2] * zc[c + 2] + za[c + 3] * zc[c + 3];
    }
    sg[t][tp] = s;
  }
  __syncthreads();
  if (tid >= 1 && tid < 32) {
    int t = tid;
    float cg = cgp[0], cb = cbp[0];
    float m = -3.0e38f;
    for (int tp = 0; tp < t; tp++) m = fmaxf(m, sg[t][tp]);
    float se = 0.f;
    for (int tp = 0; tp < t; tp++) se += expf(sg[t][tp] - m);
    float inv = 1.0f / se;
    float wcs = 0.f;
    for (int tp = 0; tp < t; tp++) {
      float s = sg[t][tp];
      float w = expf(s - m) * inv;
      warr[(size_t)b * 1024 + t * 32 + tp] = w;
      wcs = fmaf(w, sigf(fmaf(s, cg, cb)), wcs);
    }
    wc[b * 32 + t] = wcs;
  }
}

// ---------------- per-step gates: h = act(keyr @ Wx + b) ----------------
// grid 256 WGs (16 rowtiles x 16 hctiles), 256 thr.
// tile 32r x 32hc (x3 gates); 8-way k-split; micro 8r x 4hc x 3g.
__global__ __launch_bounds__(256) void k_gates(const float* __restrict__ Wx,
                                               const float* __restrict__ lb,
                                               const float* __restrict__ keyrT,
                                               float* __restrict__ h, int t)
{
  __shared__ float smem[12800];  // union: AsT[32][36]+Bs[32][100] | Rb[128][100]
  float* AsT = smem;             // stride 36
  float* Bs  = smem + 1152;      // stride 100, [kk][g*32 + hc]
  float* Rb  = smem;             // stride 100, layout r*12 + {I:0-3,C:4-7,O:8-11}
  const int tid = threadIdx.x;
  const int rt = blockIdx.x >> 4;
  const int ct = blockIdx.x & 15;
  const int row0 = rt * 32;
  const int hc0 = ct * 32;
  const int pos = tid & 31;
  const int rg = pos >> 3;       // 0..3  rows rg*8..+7
  const int cg = pos & 7;        // 0..7  hcols cg*4..+3
  const int ksub = tid >> 5;     // 0..7
  const int kkA = tid >> 3;      // staging: kk row 0..31
  const int lA = (tid & 7) * 4;  // staging: lane float4

  float4 accI[8], accC[8], accO[8];
#pragma unroll
  for (int r = 0; r < 8; r++) {
    accI[r] = make_float4(0.f, 0.f, 0.f, 0.f);
    accC[r] = make_float4(0.f, 0.f, 0.f, 0.f);
    accO[r] = make_float4(0.f, 0.f, 0.f, 0.f);
  }

  if (t > 0) {
    for (int c = 0; c < 8; c++) {
      const int k0 = c * 32;
      if (c) __syncthreads();
      // stage A (keyrT[k][row]) and B (Wx[k][gatecols])
      {
        float4 av = *(const float4*)&keyrT[(size_t)(k0 + kkA) * 512 + row0 + lA];
        *(float4*)&AsT[kkA * 36 + lA] = av;
        const size_t wrow = (size_t)(k0 + kkA) * 2048;
        float4 b0 = *(const float4*)&Wx[wrow + hc0 + lA];
        float4 b1 = *(const float4*)&Wx[wrow + 1024 + hc0 + lA];
        float4 b2 = *(const float4*)&Wx[wrow + 1536 + hc0 + lA];
        *(float4*)&Bs[kkA * 100 + 0  + lA] = b0;
        *(float4*)&Bs[kkA * 100 + 32 + lA] = b1;
        *(float4*)&Bs[kkA * 100 + 64 + lA] = b2;
      }
      __syncthreads();
#pragma unroll
      for (int i = 0; i < 4; i++) {
        const int kk = ksub * 4 + i;
        float a8[8];
        *(float4*)&a8[0] = *(const float4*)&AsT[kk * 36 + rg * 8];
        *(float4*)&a8[4] = *(const float4*)&AsT[kk * 36 + rg * 8 + 4];
        float4 bI = *(const float4*)&Bs[kk * 100 + 0  + cg * 4];
        float4 bC = *(const float4*)&Bs[kk * 100 + 32 + cg * 4];
        float4 bO = *(const float4*)&Bs[kk * 100 + 64 + cg * 4];
#pragma unroll
        for (int r = 0; r < 8; r++) {
          float a = a8[r];
          accI[r] = f4fma(a, bI, accI[r]);
          accC[r] = f4fma(a, bC, accC[r]);
          accO[r] = f4fma(a, bO, accO[r]);
        }
      }
    }
    // tail k = 256 (ksub 0 threads cover all 32 positions)
    if (ksub == 0) {
      float a8[8];
      *(float4*)&a8[0] = *(const float4*)&keyrT[(size_t)256 * 512 + row0 + rg * 8];
      *(float4*)&a8[4] = *(const float4*)&keyrT[(size_t)256 * 512 + row0 + rg * 8 + 4];
      const size_t wrow = (size_t)256 * 2048;
      float4 bI = *(const float4*)&Wx[wrow + hc0 + cg * 4];
      float4 bC = *(const float4*)&Wx[wrow + 1024 + hc0 + cg * 4];
      float4 bO = *(const float4*)&Wx[wrow + 1536 + hc0 + cg * 4];
#pragma unroll
      for (int r = 0; r < 8; r++) {
        float a = a8[r];
        accI[r] = f4fma(a, bI, accI[r]);
        accC[r] = f4fma(a, bC, accC[r]);
        accO[r] = f4fma(a, bO, accO[r]);
      }
    }
  }

  // k-split tree reduction: 8 partials -> position holders (tids 0..31)
  for (int half = 128; half >= 32; half >>= 1) {
    __syncthreads();
    if (tid >= half && tid < 2 * half) {
      float* w = &Rb[(tid - half) * 100];
#pragma unroll
      for (int r = 0; r < 8; r++) {
        *(float4*)&w[r * 12 + 0] = accI[r];
        *(float4*)&w[r * 12 + 4] = accC[r];
        *(float4*)&w[r * 12 + 8] = accO[r];
      }
    }
    __syncthreads();
    if (tid < half) {
      const float* p = &Rb[tid * 100];
#pragma unroll
      for (int r = 0; r < 8; r++) {
        accI[r] = f4add(accI[r], *(const float4*)&p[r * 12 + 0]);
        accC[r] = f4add(accC[r], *(const float4*)&p[r * 12 + 4]);
        accO[r] = f4add(accO[r], *(const float4*)&p[r * 12 + 8]);
      }
    }
  }
  __syncthreads();
  if (tid < 32) {
    float* w = &Rb[tid * 100];
#pragma unroll
    for (int r = 0; r < 8; r++) {
      *(float4*)&w[r * 12 + 0] = accI[r];
      *(float4*)&w[r * 12 + 4] = accC[r];
      *(float4*)&w[r * 12 + 8] = accO[r];
    }
  }
  __syncthreads();
  // redistribute: 256 threads each finalize 4 h-elements
  {
    const int f = tid >> 3;       // finalist position 0..31
    const int r = tid & 7;        // row within micro-tile
    const float* p = &Rb[f * 100 + r * 12];
    float4 vI = *(const float4*)&p[0];
    float4 vC = *(const float4*)&p[4];
    float4 vO = *(const float4*)&p[8];
    const int row = row0 + (f >> 3) * 8 + r;
    const int hcb = hc0 + (f & 7) * 4;
    float4 lI = *(const float4*)&lb[hcb];
    float4 lC = *(const float4*)&lb[1024 + hcb];
    float4 lO = *(const float4*)&lb[1536 + hcb];
    float hv[4];
    {
      float iv[4] = {vI.x + lI.x, vI.y + lI.y, vI.z + lI.z, vI.w + lI.w};
      float cv[4] = {vC.x + lC.x, vC.y + lC.y, vC.z + lC.z, vC.w + lC.w};
      float ov[4] = {vO.x + lO.x, vO.y + lO.y, vO.z + lO.z, vO.w + lO.w};
#pragma unroll
      for (int j = 0; j < 4; j++) {
        float cn = sigf(iv[j]) * tanhf(cv[j]);
        hv[j] = sigf(ov[j]) * tanhf(cn);
      }
    }
    *(float4*)&h[(size_t)row * 512 + hcb] = make_float4(hv[0], hv[1], hv[2], hv[3]);
  }
}

// ---------------- per-step update: keyw->Mk[t], gate, keyrT ----------------
// grid 128 WGs (16 rowtiles x 8 coltiles), 256 thr.
// tile 32r x 32c; 16-way k-split; micro 8r x 8c.
__global__ __launch_bounds__(256) void k_update(const float* __restrict__ h,
                                                const float* __restrict__ kW,
                                                const float* __restrict__ kb,
                                                const float* __restrict__ gW,
                                                const float* __restrict__ gb,
                                                const float* __restrict__ warr,
                                                const float* __restrict__ wc,
                                                float* __restrict__ Mk,
                                                float* __restrict__ keyrT, int t)
{
  __shared__ float smem[8704];   // union: hsT[32][36]+kWs[32][36] | Rb[128][68] | wws[32][33]+gsh[32]
  float* hsT = smem;             // stride 36
  float* kWs = smem + 1152;      // stride 36
  float* Rb  = smem;             // stride 68, layout r*8 + c
  float* wws = smem;             // [32][33]
  float* gsh = smem + 1056;      // [32]
  const int tid = threadIdx.x;
  const int rt = blockIdx.x >> 3;
  const int ct = blockIdx.x & 7;
  const int row0 = rt * 32;
  const int col0 = ct * 32;
  const int pos = tid & 15;
  const int rg = pos >> 2;       // rows rg*8..+7
  const int cg = pos & 3;        // cols cg*8..+7
  const int ksub = tid >> 4;     // 0..15
  const int rH = tid >> 3;       // staging row 0..31
  const int cH = (tid & 7) * 4;  // staging float4

  float4 acc[8][2];
#pragma unroll
  for (int r = 0; r < 8; r++) {
    acc[r][0] = make_float4(0.f, 0.f, 0.f, 0.f);
    acc[r][1] = make_float4(0.f, 0.f, 0.f, 0.f);
  }

  for (int c = 0; c < 16; c++) {
    const int k0 = c * 32;
    if (c) __syncthreads();
    {
      // stage h transposed: hsT[k][row]
      float4 hv = *(const float4*)&h[(size_t)(row0 + rH) * 512 + k0 + cH];
      hsT[(cH + 0) * 36 + rH] = hv.x;
      hsT[(cH + 1) * 36 + rH] = hv.y;
      hsT[(cH + 2) * 36 + rH] = hv.z;
      hsT[(cH + 3) * 36 + rH] = hv.w;
      // stage kW: kWs[k][col]
      float4 wv = *(const float4*)&kW[(size_t)(k0 + rH) * 256 + col0 + cH];
      *(float4*)&kWs[rH * 36 + cH] = wv;
    }
    __syncthreads();
#pragma unroll
    for (int i = 0; i < 2; i++) {
      const int kk = ksub * 2 + i;
      float a8[8];
      *(float4*)&a8[0] = *(const float4*)&hsT[kk * 36 + rg * 8];
      *(float4*)&a8[4] = *(const float4*)&hsT[kk * 36 + rg * 8 + 4];
      float4 b0 = *(const float4*)&kWs[kk * 36 + cg * 8];
      float4 b1 = *(const float4*)&kWs[kk * 36 + cg * 8 + 4];
#pragma unroll
      for (int r = 0; r < 8; r++) {
        float a = a8[r];
        acc[r][0] = f4fma(a, b0, acc[r][0]);
        acc[r][1] = f4fma(a, b1, acc[r][1]);
      }
    }
  }

  // reduce 16 partials -> tids 0..15
  for (int half = 128; half >= 16; half >>= 1) {
    __syncthreads();
    if (tid >= half && tid < 2 * half) {
      float* w = &Rb[(tid - half) * 68];
#pragma unroll
      for (int r = 0; r < 8; r++) {
        *(float4*)&w[r * 8 + 0] = acc[r][0];
        *(float4*)&w[r * 8 + 4] = acc[r][1];
      }
    }
    __syncthreads();
    if (tid < half) {
      const float* p = &Rb[tid * 68];
#pragma unroll
      for (int r = 0; r < 8; r++) {
        acc[r][0] = f4add(acc[r][0], *(const float4*)&p[r * 8 + 0]);
        acc[r][1] = f4add(acc[r][1], *(const float4*)&p[r * 8 + 4]);
      }
    }
  }
  __syncthreads();
  if (tid < 16) {
    float* w = &Rb[tid * 68];
#pragma unroll
    for (int r = 0; r < 8; r++) {
      *(float4*)&w[r * 8 + 0] = acc[r][0];
      *(float4*)&w[r * 8 + 4] = acc[r][1];
    }
  }
  __syncthreads();
  // Mk write (+kb): 256 threads x 4 elems
  {
    const int f = tid >> 4;
    const int idx = tid & 15;
    const int r = idx >> 1;
    const int c4 = (idx & 1) * 4;
    float4 v = *(const float4*)&Rb[f * 68 + r * 8 + c4];
    const int row = row0 + (f >> 2) * 8 + r;
    const int col = col0 + (f & 3) * 8 + c4;
    float4 kb4 = *(const float4*)&kb[col];
    *(float4*)&Mk[(size_t)row * 8192 + t * 256 + col] =
        make_float4(v.x + kb4.x, v.y + kb4.y, v.z + kb4.z, v.w + kb4.w);
  }
  __syncthreads();
  // gate phase + wws load
  {
    const int gr = tid >> 3, gp = tid & 7;
    float4 s4 = make_float4(0.f, 0.f, 0.f, 0.f);
    const float* hrow = &h[(size_t)(row0 + gr) * 512 + gp * 64];
    const float* gwp = &gW[gp * 64];
#pragma unroll 4
    for (int i4 = 0; i4 < 16; i4++) {
      float4 hv = *(const float4*)&hrow[i4 * 4];
      float4 gv = *(const float4*)&gwp[i4 * 4];
      s4.x = fmaf(hv.x, gv.x, s4.x);
      s4.y = fmaf(hv.y, gv.y, s4.y);
      s4.z = fmaf(hv.z, gv.z, s4.z);
      s4.w = fmaf(hv.w, gv.w, s4.w);
    }
    float s = s4.x + s4.y + s4.z + s4.w;
    s += __shfl_xor(s, 1);
    s += __shfl_xor(s, 2);
    s += __shfl_xor(s, 4);
    if (gp == 0) gsh[gr] = sigf(s + gb[0]);
    if (t > 0) {
      float4 wv = *(const float4*)&warr[(size_t)(row0 + gr) * 1024 + t * 32 + gp * 4];
      wws[gr * 33 + gp * 4 + 0] = wv.x;
      wws[gr * 33 + gp * 4 + 1] = wv.y;
      wws[gr * 33 + gp * 4 + 2] = wv.z;
      wws[gr * 33 + gp * 4 + 3] = wv.w;
    }
  }
  __syncthreads();
  // weighted Mk sum -> keyrT (transposed write)
  {
    const int r2 = tid >> 3;
    const int p2 = tid & 7;
    const int row = row0 + r2;
    if (t == 0) {
#pragma unroll
      for (int j = 0; j < 4; j++) keyrT[(size_t)(col0 + p2 * 4 + j) * 512 + row] = 0.f;
      if (ct == 0 && p2 == 0) keyrT[(size_t)256 * 512 + row] = 0.f;
    } else {
      float4 a4 = make_float4(0.f, 0.f, 0.f, 0.f);
      const float* mkb = Mk + (size_t)row * 8192 + col0 + p2 * 4;
      for (int tp = 0; tp < t; tp++) {
        float w = wws[r2 * 33 + tp];
        a4 = f4fma(w, *(const float4*)&mkb[tp * 256], a4);
      }
      float g = gsh[r2];
      keyrT[(size_t)(col0 + p2 * 4 + 0) * 512 + row] = g * a4.x;
      keyrT[(size_t)(col0 + p2 * 4 + 1) * 512 + row] = g * a4.y;
      keyrT[(size_t)(col0 + p2 * 4 + 2) * 512 + row] = g * a4.z;
      keyrT[(size_t)(col0 + p2 * 4 + 3) * 512 + row] = g * a4.w;
      if (ct == 0 && p2 == 0) {
        keyrT[(size_t)256 * 512 + row] = g * wc[row * 32 + t];
      }
    }
  }
}

// ---------------- final: y = h @ yW + yb, argmax ----------------
__global__ __launch_bounds__(256) void k_y(const float* __restrict__ h,
                                           const float* __restrict__ yW,
                                           const float* __restrict__ yb,
                                           float* __restrict__ out)
{
  int tid = threadIdx.x;
  int wave = tid >> 6, lane = tid & 63;
  int row = blockIdx.x * 4 + wave;
  float a0 = 0.f, a1 = 0.f, a2 = 0.f, a3 = 0.f;
  for (int k = lane; k < 512; k += 64) {
    float hv = h[(size_t)row * 512 + k];
    float4 w4 = *(const float4*)(yW + k * 4);
    a0 = fmaf(hv, w4.x, a0);
    a1 = fmaf(hv, w4.y, a1);
    a2 = fmaf(hv, w4.z, a2);
    a3 = fmaf(hv, w4.w, a3);
  }
#pragma unroll
  for (int off = 32; off > 0; off >>= 1) {
    a0 += __shfl_xor(a0, off);
    a1 += __shfl_xor(a1, off);
    a2 += __shfl_xor(a2, off);
    a3 += __shfl_xor(a3, off);
  }
  if (lane == 0) {
    a0 += yb[0]; a1 += yb[1]; a2 += yb[2]; a3 += yb[3];
    out[row * 4 + 0] = a0;
    out[row * 4 + 1] = a1;
    out[row * 4 + 2] = a2;
    out[row * 4 + 3] = a3;
    int bi = 0; float bv = a0;
    if (a1 > bv) { bv = a1; bi = 1; }
    if (a2 > bv) { bv = a2; bi = 2; }
    if (a3 > bv) { bv = a3; bi = 3; }
    out[2048 + row] = (float)bi;
  }
}

extern "C" void kernel_launch(void* const* d_in, const int* in_sizes, int n_in,
                              void* d_out, int out_size, void* d_ws, size_t ws_size,
                              hipStream_t stream)
{
  const float* x  = (const float*)d_in[0];
  const float* w1 = (const float*)d_in[1];
  const float* b1 = (const float*)d_in[2];
  const float* w2 = (const float*)d_in[3];
  const float* b2 = (const float*)d_in[4];
  const float* Wx = (const float*)d_in[5];
  const float* lb = (const float*)d_in[6];
  const float* kW = (const float*)d_in[7];
  const float* kb = (const float*)d_in[8];
  const float* gW = (const float*)d_in[9];
  const float* gb = (const float*)d_in[10];
  const float* yW = (const float*)d_in[11];
  const float* yb = (const float*)d_in[12];
  const float* cg = (const float*)d_in[13];
  const float* cb = (const float*)d_in[14];
  float* out = (float*)d_out;
  char* ws = (char*)d_ws;
  // ws layout:
  //  C1 @ [0, 33.55MB)  (dead after k_gemm2; region reused below)
  //    Mk    @ 0          (16.78MB)  [512][32][256] f32
  //    warr  @ 16777216   (2MB)      [512][32][32]  f32
  //    wc    @ 18874368   (64KB)     [512][32]      f32
  //    keyrT @ 18939904   (526KB)    [257][512]     f32 (transposed)
  //    h     @ 19466240   (1MB)      [512][512]     f32
  //  zp @ 33554432        (8.65MB)   [512][33][128] f32
  float* C1    = (float*)(ws);
  float* Mk    = (float*)(ws);
  float* warr  = (float*)(ws + 16777216);
  float* wcb   = (float*)(ws + 18874368);
  float* keyrT = (float*)(ws + 18939904);
  float* h     = (float*)(ws + 19466240);
  float* zp    = (float*)(ws + 33554432);

  hipLaunchKernelGGL(k_gemm1, dim3(512), dim3(256), 0, stream, x, w1, b1, C1);
  hipLaunchKernelGGL(k_gemm2, dim3(128), dim3(256), 0, stream, C1, w2, b2, zp);
  hipLaunchKernelGGL(k_gram, dim3(512), dim3(256), 0, stream, zp, warr, wcb, cg, cb);
  for (int t = 0; t <= 32; t++) {
    hipLaunchKernelGGL(k_gates, dim3(256), dim3(256), 0, stream, Wx, lb, keyrT, h, t);
    if (t < 32) {
      hipLaunchKernelGGL(k_update, dim3(128), dim3(256), 0, stream,
                         h, kW, kb, gW, gb, warr, wcb, Mk, keyrT, t);
    }
  }
  hipLaunchKernelGGL(k_y, dim3(128), dim3(256), 0, stream, h, yW, yb, out);
}